// Round 2
// baseline (712.412 us; speedup 1.0000x reference)
//
#include <hip/hip_runtime.h>

// CT parallel-beam pixel-driven back-projection. Static geometry.
#define BATCH 8
#define NVIEW 720
#define NDET  736
#define IMGH  512
#define IMGW  512
#define PPT   8   // pixels per thread along w: w, w+64, ..., w+448

#define DANG_F  ((float)(6.283185307179586 / 720.0))
#define RATIO_F ((float)(0.006641 / 0.0066))
#define UCENTER ((float)((NDET - 1) * 0.5))

// Block = 256 threads: lanes 0..63 cover w%64, 4 waves cover 4 h-rows.
// Each thread owns 8 pixels strided 64 in w -> all stores/gathers coalesced.
// Bounds check removed: |px*c + py*s| <= 257.1*sqrt(2) = 363.6 < 367.5, so
// u in [3.9, 731.1] and both taps are always in [0, NDET-1].
__global__ __launch_bounds__(256) void backproject_kernel(
    const float* __restrict__ proj,  // [B, V, D]
    float* __restrict__ out)         // [B, H, W]
{
    __shared__ float2 cs[NVIEW];  // (cos*r, sin*r) per view

    for (int v = threadIdx.x; v < NVIEW; v += 256) {
        float ang = (float)v * DANG_F;
        float s, c;
        sincosf(ang, &s, &c);
        cs[v] = make_float2(c * RATIO_F, s * RATIO_F);
    }
    __syncthreads();

    const int b    = blockIdx.z;
    const int lane = threadIdx.x & 63;
    const int h    = blockIdx.y * 4 + (threadIdx.x >> 6);

    const float px0 = (float)lane - (float)(IMGW - 1) * 0.5f;
    const float py  = (float)(IMGH - 1) * 0.5f - (float)h;

    const float* __restrict__ sino = proj + (size_t)b * NVIEW * NDET;

    float acc[PPT];
#pragma unroll
    for (int p = 0; p < PPT; ++p) acc[p] = 0.0f;

#pragma unroll 2
    for (int v = 0; v < NVIEW; ++v) {
        const float2 t = cs[v];
        const float ub = fmaf(px0, t.x, fmaf(py, t.y, UCENTER));
        const float* __restrict__ row = sino + v * NDET;
#pragma unroll
        for (int p = 0; p < PPT; ++p) {
            // independent u per pixel (no serial chain): u + 64p*cx
            const float u  = (p == 0) ? ub : fmaf((float)(64 * p), t.x, ub);
            const float u0 = floorf(u);
            const float fr = u - u0;
            const int i0   = (int)u0;
            const float v0 = row[i0];
            const float v1 = row[i0 + 1];   // offset:4 off the same address
            acc[p] += fmaf(fr, v1 - v0, v0);
        }
    }

    float* __restrict__ o = out + ((size_t)b * IMGH + h) * IMGW + lane;
#pragma unroll
    for (int p = 0; p < PPT; ++p) o[64 * p] = acc[p] * DANG_F;
}

extern "C" void kernel_launch(void* const* d_in, const int* in_sizes, int n_in,
                              void* d_out, int out_size, void* d_ws, size_t ws_size,
                              hipStream_t stream) {
    const float* proj = (const float*)d_in[0];
    float* out = (float*)d_out;

    dim3 block(256, 1, 1);
    dim3 grid(1, IMGH / 4, BATCH);  // 1024 blocks = 4 blocks/CU
    backproject_kernel<<<grid, block, 0, stream>>>(proj, out);
}

// Round 3
// 531.882 us; speedup vs baseline: 1.3394x; 1.3394x over previous
//
#include <hip/hip_runtime.h>

// CT parallel-beam pixel-driven back-projection. Static geometry.
// Strategy: opposing views (v, v+360) have u' = 735 - u, so staging row v+360
// REVERSED in LDS lets both views share one (i0, fr): fused 2-view interp.
// Rows are staged global->LDS double-buffered with register prefetch; pixel
// gathers become ds_read2_b32 at ~stride-1 (bank-conflict-free).
#define BATCH 8
#define NVIEW 720
#define NPAIR 360
#define NDET  736
#define IMGH  512
#define IMGW  512

#define DANG_F  ((float)(6.283185307179586 / 720.0))
#define RATIO_F ((float)(0.006641 / 0.0066))
#define UCENTER ((float)((NDET - 1) * 0.5))

// Staging: 2 rows x 736 floats = 368 float4-chunks, 256 threads.
// chunk c<184: row A chunk c. chunk c>=184: row B chunk c-184 (written reversed).
// Thread t owns chunk t (always) and chunk t+256 (if t<112).
__device__ __forceinline__ void load_pair(const float* __restrict__ sino,
                                          int pair, int tid,
                                          float4& ra, float4& rb) {
    const float* rowA = sino + pair * NDET;
    const float* rowB = sino + (pair + NPAIR) * NDET;
    if (tid < 184) ra = *(const float4*)(rowA + 4 * tid);
    else           ra = *(const float4*)(rowB + 4 * (tid - 184));
    if (tid < 112) rb = *(const float4*)(rowB + 4 * (tid + 72));
}

__device__ __forceinline__ void write_pair(float* __restrict__ A,
                                           float* __restrict__ Bv,
                                           int tid, float4 ra, float4 rb) {
    if (tid < 184) {
        *(float4*)(A + 4 * tid) = ra;
    } else {
        const int i = 4 * (tid - 184);
        // Bv[735-j] = rowB[j]: reversed float4 at 732-i (16B aligned).
        *(float4*)(Bv + (732 - i)) = make_float4(ra.w, ra.z, ra.y, ra.x);
    }
    if (tid < 112) {
        const int i = 4 * (tid + 72);
        *(float4*)(Bv + (732 - i)) = make_float4(rb.w, rb.z, rb.y, rb.x);
    }
}

// Block = 256 threads: lanes 0..63 = consecutive w, 4 waves = 4 h rows,
// 4 pixels/thread strided 64 in w -> tile 256w x 4h. Grid 2048 = 8 blocks/CU.
// Bounds check proven unnecessary: |px*cx+py*cy| <= 363.6 < 367.5 so
// u in [3.9, 731.1]; i0+1 <= 732 < 736 always.
__global__ __launch_bounds__(256, 8) void backproject_kernel(
    const float* __restrict__ proj,  // [B, V, D]
    float* __restrict__ out)         // [B, H, W]
{
    __shared__ alignas(16) float ldsA[2][NDET];
    __shared__ alignas(16) float ldsB[2][NDET];
    __shared__ float2 cs[NPAIR];

    const int tid = threadIdx.x;

    for (int v = tid; v < NPAIR; v += 256) {
        float s, c;
        sincosf((float)v * DANG_F, &s, &c);
        cs[v] = make_float2(c * RATIO_F, s * RATIO_F);
    }

    const int b    = blockIdx.z;
    const int lane = tid & 63;
    const int h    = (int)blockIdx.y * 4 + (tid >> 6);
    const int w0   = (int)blockIdx.x * 256 + lane;

    const float px0 = (float)w0 - (float)(IMGW - 1) * 0.5f;
    const float py  = (float)(IMGH - 1) * 0.5f - (float)h;

    const float* __restrict__ sino = proj + (size_t)b * NVIEW * NDET;

    float acc[4] = {0.f, 0.f, 0.f, 0.f};

    float4 ra, rb;
    load_pair(sino, 0, tid, ra, rb);
    write_pair(ldsA[0], ldsB[0], tid, ra, rb);
    load_pair(sino, 1, tid, ra, rb);
    __syncthreads();

    for (int pair = 0; pair < NPAIR; ++pair) {
        const int buf = pair & 1;
        const float2 t = cs[pair];
        const float ub = fmaf(px0, t.x, fmaf(py, t.y, UCENTER));
        const float* __restrict__ A  = ldsA[buf];
        const float* __restrict__ Bv = ldsB[buf];
#pragma unroll
        for (int p = 0; p < 4; ++p) {
            const float u  = (p == 0) ? ub : fmaf((float)(64 * p), t.x, ub);
            const float u0 = floorf(u);
            const float fr = u - u0;
            const int i0   = (int)u0;
            const float a0 = A[i0], a1 = A[i0 + 1];     // ds_read2_b32
            const float b0 = Bv[i0], b1 = Bv[i0 + 1];   // ds_read2_b32
            const float s0 = a0 + b0;
            const float s1 = a1 + b1;
            acc[p] += fmaf(fr, s1 - s0, s0);
        }
        if (pair < NPAIR - 1) {
            // lds[buf^1] was last read at iter pair-1, sealed by that
            // iteration's barrier -> safe to overwrite now.
            write_pair(ldsA[buf ^ 1], ldsB[buf ^ 1], tid, ra, rb);
            if (pair < NPAIR - 2) load_pair(sino, pair + 2, tid, ra, rb);
            __syncthreads();
        }
    }

    float* __restrict__ o = out + ((size_t)b * IMGH + h) * IMGW + w0;
#pragma unroll
    for (int p = 0; p < 4; ++p) o[64 * p] = acc[p] * DANG_F;
}

extern "C" void kernel_launch(void* const* d_in, const int* in_sizes, int n_in,
                              void* d_out, int out_size, void* d_ws, size_t ws_size,
                              hipStream_t stream) {
    const float* proj = (const float*)d_in[0];
    float* out = (float*)d_out;

    dim3 block(256, 1, 1);
    dim3 grid(IMGW / 256, IMGH / 4, BATCH);  // 2048 blocks = 8/CU exactly
    backproject_kernel<<<grid, block, 0, stream>>>(proj, out);
}